// Round 1
// baseline (715.875 us; speedup 1.0000x reference)
//
#include <hip/hip_runtime.h>
#include <math.h>

// Problem constants (from reference setup_inputs): n=16, b=4, t=2048, h=1024
#define H     1024
#define NBLK  16
#define BT    8192                 // b * t
#define ROUTED_SIZE (BT * H)       // 8,388,608 floats
#define SCALE_INV (1.0f / 32.0f)   // 1 / (sqrt(1024) * BASE_TAU)

__global__ __launch_bounds__(256, 4) void block_attn_res_kernel(
    const float* __restrict__ values,        // [16, 4, 2048, 1024]
    const float* __restrict__ w_query,       // [24, 1024]
    const float* __restrict__ key_pos_bias,  // [24, 1024]
    const int*   __restrict__ position_p,    // scalar (16)
    float*       __restrict__ out)           // routed [4,2048,1024] ++ alpha [4,2048,16]
{
    const int bt   = blockIdx.x;      // 0..8191  (b*2048 + t)
    const int tid  = threadIdx.x;     // 0..255
    const int lane = tid & 63;
    const int wave = tid >> 6;
    const int h0   = tid << 2;        // this thread's 4 h-elements

    const int pos = *position_p;      // 16

    // Query fragment for this thread's h-slice.
    const float4 q = *(const float4*)(w_query + (size_t)pos * H + h0);

    // Load all 16 value fragments (one HBM read of values total, kept in VGPRs).
    float4 v[NBLK];
    const float* vbase = values + (size_t)bt * H + h0;
#pragma unroll
    for (int n = 0; n < NBLK; ++n)
        v[n] = *(const float4*)(vbase + (size_t)n * (size_t)BT * H);

    // Per-n block reductions: SS = sum(v*v), QV = sum(q*v), QB = sum(q*bias[n]).
    __shared__ float red[3][NBLK][4];

#pragma unroll
    for (int n = 0; n < NBLK; ++n) {
        const float4 bn = *(const float4*)(key_pos_bias + (size_t)n * H + h0);
        float ss = v[n].x * v[n].x + v[n].y * v[n].y + v[n].z * v[n].z + v[n].w * v[n].w;
        float qv = q.x * v[n].x + q.y * v[n].y + q.z * v[n].z + q.w * v[n].w;
        float qb = q.x * bn.x + q.y * bn.y + q.z * bn.z + q.w * bn.w;
#pragma unroll
        for (int off = 32; off > 0; off >>= 1) {
            ss += __shfl_down(ss, off, 64);
            qv += __shfl_down(qv, off, 64);
            qb += __shfl_down(qb, off, 64);
        }
        if (lane == 0) {
            red[0][n][wave] = ss;
            red[1][n][wave] = qv;
            red[2][n][wave] = qb;
        }
    }
    __syncthreads();

    // Every thread redundantly finishes the reduction + softmax over n (16 values).
    float score[NBLK];
    float m = -3.402823466e38f;
#pragma unroll
    for (int n = 0; n < NBLK; ++n) {
        const float SS = red[0][n][0] + red[0][n][1] + red[0][n][2] + red[0][n][3];
        const float QV = red[1][n][0] + red[1][n][1] + red[1][n][2] + red[1][n][3];
        const float QB = red[2][n][0] + red[2][n][1] + red[2][n][2] + red[2][n][3];
        const float inv = rsqrtf(SS * (1.0f / (float)H) + 1e-6f);
        score[n] = (inv * QV + QB) * SCALE_INV;
        m = fmaxf(m, score[n]);
    }
    float sum = 0.0f;
#pragma unroll
    for (int n = 0; n < NBLK; ++n) {
        score[n] = __expf(score[n] - m);
        sum += score[n];
    }
    const float rs = 1.0f / sum;

    // routed[b,t,h] = sum_n alpha[n] * values[n,b,t,h]
    float4 acc = make_float4(0.0f, 0.0f, 0.0f, 0.0f);
#pragma unroll
    for (int n = 0; n < NBLK; ++n) {
        const float a = score[n] * rs;
        acc.x += a * v[n].x;
        acc.y += a * v[n].y;
        acc.z += a * v[n].z;
        acc.w += a * v[n].w;
    }
    *(float4*)(out + (size_t)bt * H + h0) = acc;

    // alpha_bth[b,t,n]
    if (tid < NBLK)
        out[(size_t)ROUTED_SIZE + (size_t)bt * NBLK + tid] = score[tid] * rs;
}

extern "C" void kernel_launch(void* const* d_in, const int* in_sizes, int n_in,
                              void* d_out, int out_size, void* d_ws, size_t ws_size,
                              hipStream_t stream) {
    const float* values       = (const float*)d_in[0];
    const float* w_query      = (const float*)d_in[1];
    const float* key_pos_bias = (const float*)d_in[2];
    const int*   position     = (const int*)d_in[3];
    float*       out          = (float*)d_out;

    hipLaunchKernelGGL(block_attn_res_kernel, dim3(BT), dim3(256), 0, stream,
                       values, w_query, key_pos_bias, position, out);
}

// Round 2
// 706.485 us; speedup vs baseline: 1.0133x; 1.0133x over previous
//
#include <hip/hip_runtime.h>
#include <math.h>

// Problem constants (from reference setup_inputs): n=16, b=4, t=2048, h=1024
#define H     1024
#define NBLK  16
#define BT    8192                 // b * t
#define ROUTED_SIZE (BT * H)       // 8,388,608 floats
#define SCALE_INV (1.0f / 32.0f)   // 1 / (sqrt(1024) * BASE_TAU)

// ---------------------------------------------------------------------------
// Pre-kernel: qb[n] = sum_h w_query[pos][h] * key_pos_bias[n][h]  (n = 0..15)
// Block-invariant in the main kernel, so compute once into d_ws.
// 1 block, 1024 threads = 16 waves; wave n reduces one bias row.
// ---------------------------------------------------------------------------
__global__ __launch_bounds__(1024) void qb_kernel(
    const float* __restrict__ w_query,
    const float* __restrict__ key_pos_bias,
    const int*   __restrict__ pos_p,
    float*       __restrict__ qb)
{
    const int n    = threadIdx.x >> 6;   // wave id = history slot
    const int lane = threadIdx.x & 63;
    const int pos  = *pos_p;

    const float* q = w_query      + (size_t)pos * H;
    const float* b = key_pos_bias + (size_t)n   * H;

    float s = 0.0f;
#pragma unroll
    for (int j = 0; j < 4; ++j) {
        const int h = lane * 16 + j * 4;           // 16 contiguous floats/lane
        const float4 qv = *(const float4*)(q + h);
        const float4 bv = *(const float4*)(b + h);
        s += qv.x * bv.x + qv.y * bv.y + qv.z * bv.z + qv.w * bv.w;
    }
#pragma unroll
    for (int off = 32; off; off >>= 1) s += __shfl_xor(s, off, 64);
    if (lane == 0) qb[n] = s;
}

// ---------------------------------------------------------------------------
// Main kernel: one 128-thread block per (b,t) column. Each thread owns 8 h
// elements as two float4s at h0 and h0+512 (both fully coalesced per instr).
// values is read from HBM exactly once (kept in VGPRs: 32 float4 = 128 regs).
// ---------------------------------------------------------------------------
__global__ __launch_bounds__(128, 2) void block_attn_res_kernel(
    const float* __restrict__ values,   // [16, 4, 2048, 1024]
    const float* __restrict__ w_query,  // [24, 1024]
    const int*   __restrict__ pos_p,    // scalar (16)
    const float* __restrict__ qb,       // [16] precomputed q·bias
    float*       __restrict__ out)      // routed [4,2048,1024] ++ alpha [4,2048,16]
{
    const int bt   = blockIdx.x;       // 0..8191
    const int tid  = threadIdx.x;      // 0..127
    const int lane = tid & 63;
    const int wave = tid >> 6;         // 0..1
    const int h0   = tid << 2;         // [0, 512)
    const int h1   = h0 + 512;         // [512, 1024)

    const int pos = *pos_p;
    const float4 q0 = *(const float4*)(w_query + (size_t)pos * H + h0);
    const float4 q1 = *(const float4*)(w_query + (size_t)pos * H + h1);

    // ---- one-shot HBM read of this column's 16 value slices ----
    float4 va[NBLK], vb[NBLK];
    const float* vbase = values + (size_t)bt * H;
#pragma unroll
    for (int n = 0; n < NBLK; ++n) {
        const float* p = vbase + (size_t)n * (size_t)BT * H;
        va[n] = *(const float4*)(p + h0);
        vb[n] = *(const float4*)(p + h1);
    }

    // ---- per-n block reductions: SS = sum v^2, QV = sum q*v ----
    __shared__ float red[2][NBLK][2];

#pragma unroll
    for (int n = 0; n < NBLK; ++n) {
        float ss = va[n].x * va[n].x + va[n].y * va[n].y
                 + va[n].z * va[n].z + va[n].w * va[n].w
                 + vb[n].x * vb[n].x + vb[n].y * vb[n].y
                 + vb[n].z * vb[n].z + vb[n].w * vb[n].w;
        float qv = q0.x * va[n].x + q0.y * va[n].y
                 + q0.z * va[n].z + q0.w * va[n].w
                 + q1.x * vb[n].x + q1.y * vb[n].y
                 + q1.z * vb[n].z + q1.w * vb[n].w;
#pragma unroll
        for (int off = 32; off; off >>= 1) {
            ss += __shfl_xor(ss, off, 64);
            qv += __shfl_xor(qv, off, 64);
        }
        if (lane == 0) { red[0][n][wave] = ss; red[1][n][wave] = qv; }
    }
    __syncthreads();

    // ---- redundant per-thread softmax over the 16 history slots ----
    float score[NBLK];
    float m = -3.402823466e38f;
#pragma unroll
    for (int n = 0; n < NBLK; ++n) {
        const float SS = red[0][n][0] + red[0][n][1];
        const float QV = red[1][n][0] + red[1][n][1];
        const float inv = rsqrtf(SS * (1.0f / (float)H) + 1e-6f);
        score[n] = (inv * QV + qb[n]) * SCALE_INV;
        m = fmaxf(m, score[n]);
    }
    float sum = 0.0f;
#pragma unroll
    for (int n = 0; n < NBLK; ++n) {
        score[n] = __expf(score[n] - m);
        sum += score[n];
    }
    const float rs = 1.0f / sum;

    // ---- routed = sum_n alpha_n * v_n ----
    float4 acc0 = make_float4(0.f, 0.f, 0.f, 0.f);
    float4 acc1 = make_float4(0.f, 0.f, 0.f, 0.f);
#pragma unroll
    for (int n = 0; n < NBLK; ++n) {
        const float a = score[n] * rs;
        acc0.x += a * va[n].x;  acc0.y += a * va[n].y;
        acc0.z += a * va[n].z;  acc0.w += a * va[n].w;
        acc1.x += a * vb[n].x;  acc1.y += a * vb[n].y;
        acc1.z += a * vb[n].z;  acc1.w += a * vb[n].w;
    }
    *(float4*)(out + (size_t)bt * H + h0) = acc0;
    *(float4*)(out + (size_t)bt * H + h1) = acc1;

    // ---- alpha_bth[b,t,n] ----
    if (tid < NBLK)
        out[(size_t)ROUTED_SIZE + (size_t)bt * NBLK + tid] = score[tid] * rs;
}

extern "C" void kernel_launch(void* const* d_in, const int* in_sizes, int n_in,
                              void* d_out, int out_size, void* d_ws, size_t ws_size,
                              hipStream_t stream) {
    const float* values       = (const float*)d_in[0];
    const float* w_query      = (const float*)d_in[1];
    const float* key_pos_bias = (const float*)d_in[2];
    const int*   position     = (const int*)d_in[3];
    float*       out          = (float*)d_out;
    float*       qb           = (float*)d_ws;   // 16 floats of scratch

    hipLaunchKernelGGL(qb_kernel, dim3(1), dim3(1024), 0, stream,
                       w_query, key_pos_bias, position, qb);
    hipLaunchKernelGGL(block_attn_res_kernel, dim3(BT), dim3(128), 0, stream,
                       values, w_query, position, qb, out);
}

// Round 3
// 698.056 us; speedup vs baseline: 1.0255x; 1.0121x over previous
//
#include <hip/hip_runtime.h>
#include <math.h>

// Problem constants (from reference setup_inputs): n=16, b=4, t=2048, h=1024
#define H     1024
#define NBLK  16
#define BT    8192                 // b * t
#define ROUTED_SIZE (BT * H)       // 8,388,608 floats
#define SCALE_INV (1.0f / 32.0f)   // 1 / (sqrt(1024) * BASE_TAU)

// ---------------------------------------------------------------------------
// Pre-kernel: qb[n] = sum_h w_query[pos][h] * key_pos_bias[n][h]  (n = 0..15)
// Block-invariant in the main kernel; computed once into d_ws.
// ---------------------------------------------------------------------------
__global__ __launch_bounds__(1024) void qb_kernel(
    const float* __restrict__ w_query,
    const float* __restrict__ key_pos_bias,
    const int*   __restrict__ pos_p,
    float*       __restrict__ qb)
{
    const int n    = threadIdx.x >> 6;   // wave id = history slot
    const int lane = threadIdx.x & 63;
    const int pos  = *pos_p;

    const float* q = w_query      + (size_t)pos * H;
    const float* b = key_pos_bias + (size_t)n   * H;

    float s = 0.0f;
#pragma unroll
    for (int j = 0; j < 4; ++j) {
        const int h = lane * 16 + j * 4;
        const float4 qv = *(const float4*)(q + h);
        const float4 bv = *(const float4*)(b + h);
        s += qv.x * bv.x + qv.y * bv.y + qv.z * bv.z + qv.w * bv.w;
    }
#pragma unroll
    for (int off = 32; off; off >>= 1) s += __shfl_xor(s, off, 64);
    if (lane == 0) qb[n] = s;
}

// ---------------------------------------------------------------------------
// Main kernel: one 256-thread block per (b,t) column; thread owns 4 h-elems.
// v[16] float4 = 64 VGPRs; fits __launch_bounds__(256,4)'s 128-VGPR cap
// -> 16 waves/CU for latency hiding (2x round-2's 8 waves/CU).
// values is read from HBM exactly once.
// ---------------------------------------------------------------------------
__global__ __launch_bounds__(256, 4) void block_attn_res_kernel(
    const float* __restrict__ values,   // [16, 4, 2048, 1024]
    const float* __restrict__ w_query,  // [24, 1024]
    const int*   __restrict__ pos_p,    // scalar (16)
    const float* __restrict__ qb,       // [16] precomputed q·bias
    float*       __restrict__ out)      // routed [4,2048,1024] ++ alpha [4,2048,16]
{
    const int bt   = blockIdx.x;       // 0..8191
    const int tid  = threadIdx.x;      // 0..255
    const int lane = tid & 63;
    const int wave = tid >> 6;         // 0..3
    const int h0   = tid << 2;

    const int pos = *pos_p;
    const float4 q = *(const float4*)(w_query + (size_t)pos * H + h0);

    // ---- one-shot HBM read of this column's 16 value slices ----
    float4 v[NBLK];
    const float* vbase = values + (size_t)bt * H + h0;
#pragma unroll
    for (int n = 0; n < NBLK; ++n)
        v[n] = *(const float4*)(vbase + (size_t)n * (size_t)BT * H);

    // ---- per-n block reductions: SS = sum v^2, QV = sum q*v ----
    __shared__ float red[2][NBLK][4];

#pragma unroll
    for (int n = 0; n < NBLK; ++n) {
        float ss = v[n].x * v[n].x + v[n].y * v[n].y
                 + v[n].z * v[n].z + v[n].w * v[n].w;
        float qv = q.x * v[n].x + q.y * v[n].y
                 + q.z * v[n].z + q.w * v[n].w;
#pragma unroll
        for (int off = 32; off; off >>= 1) {
            ss += __shfl_xor(ss, off, 64);
            qv += __shfl_xor(qv, off, 64);
        }
        if (lane == 0) { red[0][n][wave] = ss; red[1][n][wave] = qv; }
    }
    __syncthreads();

    // ---- redundant per-thread softmax over the 16 history slots ----
    float score[NBLK];
    float m = -3.402823466e38f;
#pragma unroll
    for (int n = 0; n < NBLK; ++n) {
        const float SS = red[0][n][0] + red[0][n][1] + red[0][n][2] + red[0][n][3];
        const float QV = red[1][n][0] + red[1][n][1] + red[1][n][2] + red[1][n][3];
        const float inv = rsqrtf(SS * (1.0f / (float)H) + 1e-6f);
        score[n] = (inv * QV + qb[n]) * SCALE_INV;
        m = fmaxf(m, score[n]);
    }
    float sum = 0.0f;
#pragma unroll
    for (int n = 0; n < NBLK; ++n) {
        score[n] = __expf(score[n] - m);
        sum += score[n];
    }
    const float rs = 1.0f / sum;

    // ---- routed = sum_n alpha_n * v_n ----
    float4 acc = make_float4(0.f, 0.f, 0.f, 0.f);
#pragma unroll
    for (int n = 0; n < NBLK; ++n) {
        const float a = score[n] * rs;
        acc.x += a * v[n].x;  acc.y += a * v[n].y;
        acc.z += a * v[n].z;  acc.w += a * v[n].w;
    }
    *(float4*)(out + (size_t)bt * H + h0) = acc;

    // ---- alpha_bth[b,t,n] ----
    if (tid < NBLK)
        out[(size_t)ROUTED_SIZE + (size_t)bt * NBLK + tid] = score[tid] * rs;
}

extern "C" void kernel_launch(void* const* d_in, const int* in_sizes, int n_in,
                              void* d_out, int out_size, void* d_ws, size_t ws_size,
                              hipStream_t stream) {
    const float* values       = (const float*)d_in[0];
    const float* w_query      = (const float*)d_in[1];
    const float* key_pos_bias = (const float*)d_in[2];
    const int*   position     = (const int*)d_in[3];
    float*       out          = (float*)d_out;
    float*       qb           = (float*)d_ws;   // 16 floats of scratch

    hipLaunchKernelGGL(qb_kernel, dim3(1), dim3(1024), 0, stream,
                       w_query, key_pos_bias, position, qb);
    hipLaunchKernelGGL(block_attn_res_kernel, dim3(BT), dim3(256), 0, stream,
                       values, w_query, position, qb, out);
}